// Round 1
// baseline (185.407 us; speedup 1.0000x reference)
//
#include <hip/hip_runtime.h>

// DWT2d db4 — persistent blocks + double-buffered DMA prefetch pipeline.
// x: (96, 512, 512) fp32 -> out: (96*4, 256, 256) fp32
// out[bc*4+s][i][j] = sum_{p,q} x[bc][(2i+p)%512][(2j+q)%512] * fH[s][p]*fW[s][q]
//
// Structure change vs previous version: instead of one tile per block with a
// full vmcnt(0) drain between DMA and use, each block processes 12 tiles,
// prefetching tile k+1's patch (global_load_lds, fire-and-forget) while
// computing tile k. Barriers are raw s_barrier with counted waits:
//   mid-barrier:  s_waitcnt lgkmcnt(0)   (B's LDS writes visible; loads stay in flight)
//   end-barrier:  s_waitcnt vmcnt(4)     (drains the 3 prefetch loads; leaves the
//                                         4 output stores of this iter in flight)
// vmcnt never drains to 0 in the main loop.

#define TI 8                // output rows per tile
#define TJ 64               // output cols per tile
#define PR (2*TI + 6)       // 22 patch rows
#define PC 136              // padded patch cols (need 134), 34 float4 granules/row
#define NG ((PR * PC) / 4)  // 748 float4 granules in patch
#define HH 512
#define WW 512
#define NTILES 12288        // (256/TJ)*(256/TI)*96 = 4*32*96
#define GRID 1024           // 4 blocks/CU resident (LDS-limited), persistent
#define TPB (NTILES / GRID) // 12 tiles per block

typedef float v2f __attribute__((ext_vector_type(2)));
typedef const __attribute__((address_space(1))) void gas_t;   // global
typedef __attribute__((address_space(3))) void las_t;         // LDS

// Fire-and-forget DMA of one 22x134 patch into lds_base (linear, DMA-ordered).
__device__ __forceinline__ void stage_tile(const float* __restrict__ x, int tile,
                                           char* lds_base, int tid, int wid) {
    const int jt = tile & 3;
    const int it = (tile >> 2) & 31;
    const int bc = tile >> 7;
    const float* xb = x + (size_t)bc * (HH * WW);
    const int rowBase = it * (2 * TI);
    const int colBase = jt * (2 * TJ);
#pragma unroll
    for (int k = 0; k < 3; ++k) {
        int g = k * 256 + tid;                       // flat float4 granule index
        // wave-uniform LDS dest: hw adds lane*16
        las_t* lp = (las_t*)(lds_base + k * 4096 + wid * 1024);
        if (g < NG) {
            int r  = g / 34;
            int c4 = g - r * 34;
            int gr = rowBase + r;      if (gr >= HH) gr -= HH;
            int gc = colBase + 4 * c4; if (gc >= WW) gc -= WW;  // 16B-aligned, no row cross
            __builtin_amdgcn_global_load_lds((gas_t*)(xb + gr * WW + gc), lp, 16, 0, 0);
        }
    }
}

__global__ __launch_bounds__(256, 4)
void dwt2d_db4_kernel(const float* __restrict__ x,
                      const float* __restrict__ dec,
                      float* __restrict__ out) {
    __shared__ __align__(16) float sm_x[2][PR * PC];  // 2 x 11968 B (double-buffered patch)
    __shared__ __align__(16) float sm_lo[PR][TJ];     //  5632 B
    __shared__ __align__(16) float sm_hi[PR][TJ];     //  5632 B  -> total 35200 B, 4 blocks/CU

    const int tid = threadIdx.x;
    const int wid = tid >> 6;

    float flo[8], fhi[8];
#pragma unroll
    for (int k = 0; k < 8; ++k) { flo[k] = dec[k]; fhi[k] = dec[8 + k]; }

    // XCD-contiguous chunk assignment (bijective: GRID % 8 == 0). Vertically
    // adjacent tiles (shared halo rows) land on the same XCD's L2.
    const int bid   = blockIdx.x;
    const int chunk = (bid & 7) * (GRID / 8) + (bid >> 3);
    const int t0    = chunk * TPB;

    // ---- Prologue: stage tile 0, full drain once. ----
    stage_tile(x, t0, (char*)sm_x[0], tid, wid);
    asm volatile("s_waitcnt vmcnt(0)" ::: "memory");
    __builtin_amdgcn_sched_barrier(0);
    __builtin_amdgcn_s_barrier();

    for (int k = 0; k < TPB; ++k) {
        const int tile = t0 + k;
        const int jt = tile & 3;
        const int it = (tile >> 2) & 31;
        const int bc = tile >> 7;
        const float* bx = sm_x[k & 1];

        // ---- Prefetch next tile's patch into the other buffer (in flight
        //      across both barriers below; drained by end-of-iter vmcnt(4)). ----
        if (k + 1 < TPB)
            stage_tile(x, tile + 1, (char*)sm_x[(k + 1) & 1], tid, wid);

        // ---- Phase B: row pass. Thread -> output pair (2t,2t+1) of patch row r. ----
        for (int task = tid; task < PR * (TJ / 2); task += 256) {   // 704 tasks
            int r = task >> 5;
            int t = task & 31;
            const float* xr = &bx[r * PC + 4 * t];
            float4 v0 = *(const float4*)(xr);
            float4 v1 = *(const float4*)(xr + 4);
            float4 v2 = *(const float4*)(xr + 8);
            float w[12] = { v0.x, v0.y, v0.z, v0.w,
                            v1.x, v1.y, v1.z, v1.w,
                            v2.x, v2.y, v2.z, v2.w };
            float lo0 = 0.f, hi0 = 0.f, lo1 = 0.f, hi1 = 0.f;
#pragma unroll
            for (int q = 0; q < 8; ++q) {
                lo0 += w[q]     * flo[q];
                hi0 += w[q]     * fhi[q];
                lo1 += w[q + 2] * flo[q];
                hi1 += w[q + 2] * fhi[q];
            }
            *(float2*)&sm_lo[r][2 * t] = make_float2(lo0, lo1);
            *(float2*)&sm_hi[r][2 * t] = make_float2(hi0, hi1);
        }

        // ---- Mid barrier: LDS-only drain; prefetch loads stay in flight. ----
        asm volatile("s_waitcnt lgkmcnt(0)" ::: "memory");
        __builtin_amdgcn_sched_barrier(0);
        __builtin_amdgcn_s_barrier();

        // ---- Phase C: col pass. Thread -> 2 consecutive j, all 4 subbands. ----
        {
            int i  = tid >> 5;            // 0..7
            int j0 = (tid & 31) * 2;      // 0..62
            float ll0=0.f, ll1=0.f, lh0=0.f, lh1=0.f;
            float hl0=0.f, hl1=0.f, hh0=0.f, hh1=0.f;
#pragma unroll
            for (int p = 0; p < 8; ++p) {
                float2 a = *(const float2*)&sm_lo[2 * i + p][j0];
                float2 b = *(const float2*)&sm_hi[2 * i + p][j0];
                float cl = flo[p], ch = fhi[p];
                ll0 += a.x * cl; ll1 += a.y * cl;
                lh0 += a.x * ch; lh1 += a.y * ch;
                hl0 += b.x * cl; hl1 += b.y * cl;
                hh0 += b.x * ch; hh1 += b.y * ch;
            }
            int oi = it * TI + i;
            int oj = jt * TJ + j0;
            size_t base = ((size_t)(bc * 4) * 256 + oi) * 256 + oj;
            v2f ll = { ll0, ll1 }, lh = { lh0, lh1 };
            v2f hl = { hl0, hl1 }, hh = { hh0, hh1 };
            __builtin_nontemporal_store(ll, (v2f*)&out[base]);
            __builtin_nontemporal_store(lh, (v2f*)&out[base + 1 * 65536]);
            __builtin_nontemporal_store(hl, (v2f*)&out[base + 2 * 65536]);
            __builtin_nontemporal_store(hh, (v2f*)&out[base + 3 * 65536]);
        }

        // ---- End-of-iter: drain ONLY the prefetch loads (issued before the 4
        //      stores; vmcnt counts in order -> vmcnt(4) retires all loads),
        //      then barrier so every wave's DMA has landed before next Phase B. ----
        if (k + 1 < TPB) {
            asm volatile("s_waitcnt vmcnt(4)" ::: "memory");
            __builtin_amdgcn_sched_barrier(0);
            __builtin_amdgcn_s_barrier();
        }
    }
}

extern "C" void kernel_launch(void* const* d_in, const int* in_sizes, int n_in,
                              void* d_out, int out_size, void* d_ws, size_t ws_size,
                              hipStream_t stream) {
    const float* x   = (const float*)d_in[0];
    const float* dec = (const float*)d_in[1];
    float* out = (float*)d_out;

    dim3 grid(GRID);
    dim3 block(256);
    dwt2d_db4_kernel<<<grid, block, 0, stream>>>(x, dec, out);
}

// Round 2
// 172.047 us; speedup vs baseline: 1.0777x; 1.0777x over previous
//
#include <hip/hip_runtime.h>

// DWT2d db4 — round-0 structure (1 tile/block, 2 barriers) with TI=4 for
// 8 blocks/CU (32-wave occupancy cap) + 1D grid with XCD-stripe mapping.
// x: (96, 512, 512) fp32 -> out: (96*4, 256, 256) fp32
// out[bc*4+s][i][j] = sum_{p,q} x[bc][(2i+p)%512][(2j+q)%512] * fH[s][p]*fW[s][q]

#define TI 4                // output rows per block
#define TJ 64               // output cols per block
#define PR (2*TI + 6)       // 14 patch rows
#define PC 136              // padded patch cols (need 134), 34 float4 granules/row
#define NG ((PR * PC) / 4)  // 476 float4 granules in patch
#define HH 512
#define WW 512

typedef const __attribute__((address_space(1))) void gas_t;   // global
typedef __attribute__((address_space(3))) void las_t;         // LDS

__global__ __launch_bounds__(256)
void dwt2d_db4_kernel(const float* __restrict__ x,
                      const float* __restrict__ dec,
                      float* __restrict__ out) {
    __shared__ __align__(16) float sm_x[PR * PC];   // 7616 B (flat: DMA-ordered)
    __shared__ __align__(16) float sm_lo[PR][TJ];   // 3584 B
    __shared__ __align__(16) float sm_hi[PR][TJ];   // 3584 B  -> total 14784 B, 8 blocks/CU

    const int tid = threadIdx.x;
    const int wid = tid >> 6;

    // XCD-stripe mapping: block n -> XCD n&7 (hardware round-robin).
    // XCD x owns it-range [8x, 8x+8) for every bc: per-image stripe of
    // 64+6 input rows (143 KB) stays hot in that XCD's L2 across jt/bc.
    const int n  = blockIdx.x;
    const int m  = n >> 3;
    const int jt = m & 3;                       // 0..3
    const int it = (n & 7) * 8 + ((m >> 2) & 7); // 0..63
    const int bc = m >> 5;                      // 0..95

    const int rowBase = it * (2 * TI);
    const int colBase = jt * (2 * TJ);

    float flo[8], fhi[8];
#pragma unroll
    for (int k = 0; k < 8; ++k) { flo[k] = dec[k]; fhi[k] = dec[8 + k]; }

    const float* xb = x + (size_t)bc * HH * WW;

    // ---- Phase A: async DMA patch -> LDS. 2 wave-batches of 16B granules,
    //      fire-and-forget; single drain at the barrier. ----
#pragma unroll
    for (int k = 0; k < 2; ++k) {
        int g = k * 256 + tid;                     // flat float4 granule index
        // wave-uniform LDS dest: hw adds lane*16
        las_t* lp = (las_t*)((char*)sm_x + k * 4096 + wid * 1024);
        if (g < NG) {
            int r  = g / 34;
            int c4 = g - r * 34;
            int gr = rowBase + r;  if (gr >= HH) gr -= HH;
            int gc = colBase + 4 * c4; if (gc >= WW) gc -= WW;   // 16B-aligned, no row cross
            const float* gp = xb + gr * WW + gc;
            __builtin_amdgcn_global_load_lds((gas_t*)gp, lp, 16, 0, 0);
        }
    }
    __syncthreads();

    // ---- Phase B: row pass. Thread -> output pair (2t,2t+1) of patch row r. ----
    for (int task = tid; task < PR * (TJ / 2); task += 256) {   // 448 tasks
        int r = task >> 5;
        int t = task & 31;
        const float* xr = &sm_x[r * PC + 4 * t];
        float4 v0 = *(const float4*)(xr);
        float4 v1 = *(const float4*)(xr + 4);
        float4 v2 = *(const float4*)(xr + 8);
        float w[12] = { v0.x, v0.y, v0.z, v0.w,
                        v1.x, v1.y, v1.z, v1.w,
                        v2.x, v2.y, v2.z, v2.w };
        float lo0 = 0.f, hi0 = 0.f, lo1 = 0.f, hi1 = 0.f;
#pragma unroll
        for (int q = 0; q < 8; ++q) {
            lo0 += w[q]     * flo[q];
            hi0 += w[q]     * fhi[q];
            lo1 += w[q + 2] * flo[q];
            hi1 += w[q + 2] * fhi[q];
        }
        *(float2*)&sm_lo[r][2 * t] = make_float2(lo0, lo1);
        *(float2*)&sm_hi[r][2 * t] = make_float2(hi0, hi1);
    }
    __syncthreads();

    // ---- Phase C: col pass. Thread -> 1 output pixel, all 4 subbands. ----
    {
        int i = tid >> 6;             // 0..3
        int j = tid & 63;             // 0..63
        float ll = 0.f, lh = 0.f, hl = 0.f, hh = 0.f;
#pragma unroll
        for (int p = 0; p < 8; ++p) {
            float a = sm_lo[2 * i + p][j];
            float b = sm_hi[2 * i + p][j];
            float cl = flo[p], ch = fhi[p];
            ll += a * cl; lh += a * ch;
            hl += b * cl; hh += b * ch;
        }
        int oi = it * TI + i;
        int oj = jt * TJ + j;
        size_t base = ((size_t)(bc * 4) * 256 + oi) * 256 + oj;
        __builtin_nontemporal_store(ll, &out[base]);
        __builtin_nontemporal_store(lh, &out[base + 1 * 65536]);
        __builtin_nontemporal_store(hl, &out[base + 2 * 65536]);
        __builtin_nontemporal_store(hh, &out[base + 3 * 65536]);
    }
}

extern "C" void kernel_launch(void* const* d_in, const int* in_sizes, int n_in,
                              void* d_out, int out_size, void* d_ws, size_t ws_size,
                              hipStream_t stream) {
    const float* x   = (const float*)d_in[0];
    const float* dec = (const float*)d_in[1];
    float* out = (float*)d_out;

    dim3 grid(4 * 64 * 96);              // 24576 blocks, 1D (XCD-stripe mapped)
    dim3 block(256);
    dwt2d_db4_kernel<<<grid, block, 0, stream>>>(x, dec, out);
}